// Round 1
// baseline (656.496 us; speedup 1.0000x reference)
//
#include <hip/hip_runtime.h>
#include <hip/hip_bf16.h>

// MPNN fused pipeline, all heavy math in bf16 MFMA (16x16x32), fp32 accum.
//   prep_x:  edge_x fp32 -> bf16 into h[:,0:256] (lda=768) and Xt [256][8192]
//   prep_w:  W fp32 [K][N] -> bf16 Wt [N][K]  (B^T layout for MFMA B-frags)
//   gemm_bias_relu: C = relu(A @ Wt^T + b), A bf16 row-major (lda param)
//   fused_simagg:  agg = (e @ e^T / 256) @ X  without materializing sim,
//                  flash-style: per 64-row Q tile, loop 64-row K/V tiles.
// LDS layouts use 16B-granular XOR swizzle (group ^= row&7): conflict-floor
// b128 reads, no padding, keeps global_load-compatible 16B alignment.

typedef short bf16x8 __attribute__((ext_vector_type(8)));
typedef float f32x4  __attribute__((ext_vector_type(4)));

__device__ inline short f2bf(float x) {                // fp32 -> bf16 RNE
    unsigned u = __builtin_bit_cast(unsigned, x);
    return (short)((u + 0x7fffu + ((u >> 16) & 1u)) >> 16);
}

// ---------------------------------------------------------------- prep_x
__global__ void prep_x(const float* __restrict__ X, short* __restrict__ h,
                       short* __restrict__ Xt)
{
    __shared__ short tile[32][33];
    const int r0 = blockIdx.x * 32, c0 = blockIdx.y * 32;
    const int tx = threadIdx.x, ty = threadIdx.y;      // 32 x 8
    #pragma unroll
    for (int i = 0; i < 4; ++i) {
        int row = ty + i * 8;
        short b = f2bf(X[(size_t)(r0 + row) * 256 + c0 + tx]);
        tile[row][tx] = b;
        h[(size_t)(r0 + row) * 768 + c0 + tx] = b;
    }
    __syncthreads();
    #pragma unroll
    for (int i = 0; i < 4; ++i) {
        int row = ty + i * 8;
        Xt[(size_t)(c0 + row) * 8192 + r0 + tx] = tile[tx][row];
    }
}

// ---------------------------------------------------------------- prep_w
__global__ void prep_w(const float* __restrict__ W, short* __restrict__ Wt,
                       int K, int N)
{
    __shared__ short tile[32][33];
    const int k0 = blockIdx.x * 32, n0 = blockIdx.y * 32;
    const int tx = threadIdx.x, ty = threadIdx.y;
    #pragma unroll
    for (int i = 0; i < 4; ++i) {
        int row = ty + i * 8;
        tile[row][tx] = f2bf(W[(size_t)(k0 + row) * N + n0 + tx]);
    }
    __syncthreads();
    #pragma unroll
    for (int i = 0; i < 4; ++i) {
        int row = ty + i * 8;
        Wt[(size_t)(n0 + row) * K + k0 + tx] = tile[tx][row];
    }
}

// -------------------------------------------------------- gemm_bias_relu
// out[m][n] = relu(sum_k A[m][k] * Wt[n][k] + bias[n]);  M=8192 grid.x*64
__global__ __launch_bounds__(256, 1)
void gemm_bias_relu(const short* __restrict__ A, int lda,
                    const short* __restrict__ Bt, int K,
                    const float* __restrict__ bias,
                    void* __restrict__ outp, int out_bf16, int ldo)
{
    const int m0 = blockIdx.x * 64, n0 = blockIdx.y * 64;
    const int t = threadIdx.x;
    const int w = t >> 6, l = t & 63, lr = l & 15, q = l >> 4;

    __shared__ __attribute__((aligned(16))) short As[64 * 64];
    __shared__ __attribute__((aligned(16))) short Bs[64 * 64];

    f32x4 acc[4];
    #pragma unroll
    for (int i = 0; i < 4; ++i) acc[i] = f32x4{0.f, 0.f, 0.f, 0.f};

    for (int k0 = 0; k0 < K; k0 += 64) {
        __syncthreads();
        for (int i = t; i < 64 * 8; i += 256) {
            int row = i >> 3, g = i & 7;
            *(int4*)&As[row * 64 + ((g ^ (row & 7)) << 3)] =
                *(const int4*)(A + (size_t)(m0 + row) * lda + k0 + g * 8);
            *(int4*)&Bs[row * 64 + ((g ^ (row & 7)) << 3)] =
                *(const int4*)(Bt + (size_t)(n0 + row) * K + k0 + g * 8);
        }
        __syncthreads();
        #pragma unroll
        for (int ks = 0; ks < 2; ++ks) {
            int arow = w * 16 + lr;
            bf16x8 af = *(const bf16x8*)&As[arow * 64 + (((ks*4 + q) ^ (arow & 7)) << 3)];
            #pragma unroll
            for (int nt = 0; nt < 4; ++nt) {
                int brow = nt * 16 + lr;
                bf16x8 bfg = *(const bf16x8*)&Bs[brow * 64 + (((ks*4 + q) ^ (brow & 7)) << 3)];
                acc[nt] = __builtin_amdgcn_mfma_f32_16x16x32_bf16(af, bfg, acc[nt], 0, 0, 0);
            }
        }
    }
    #pragma unroll
    for (int nt = 0; nt < 4; ++nt)
        #pragma unroll
        for (int r = 0; r < 4; ++r) {
            int m = m0 + w * 16 + q * 4 + r;      // C/D: row = quad*4 + reg
            int n = n0 + nt * 16 + lr;            //      col = lane & 15
            float v = acc[nt][r] + bias[n];
            v = v > 0.f ? v : 0.f;
            if (out_bf16) ((short*)outp)[(size_t)m * ldo + n] = f2bf(v);
            else          ((float*)outp)[(size_t)m * ldo + n] = v;
        }
}

// ---------------------------------------------------------- fused_simagg
// agg[m][:] = sum_j (e[m]·e[j]/256) * X[j][:]   -> h[:, 256+sim*256 : +256]
__global__ __launch_bounds__(256, 1)
void fused_simagg(const short* __restrict__ e1, const short* __restrict__ e2,
                  const short* __restrict__ Xt, short* __restrict__ h)
{
    const int sim = blockIdx.y;
    const short* e = sim ? e2 : e1;
    const int m0 = blockIdx.x * 64;
    const int t = threadIdx.x;
    const int w = t >> 6, l = t & 63, lr = l & 15, q = l >> 4;

    __shared__ __attribute__((aligned(16))) short Ks[64 * 256]; // [j][k] swz
    __shared__ __attribute__((aligned(16))) short Vs[256 * 64]; // [n][j] swz
    __shared__ __attribute__((aligned(16))) short Ps[64 * 64];  // [m][j] swz

    // Q fragments resident in registers: rows m0 + w*16 + lr
    bf16x8 qf[8];
    {
        const short* qrow = e + (size_t)(m0 + w * 16 + lr) * 256 + q * 8;
        #pragma unroll
        for (int kc = 0; kc < 8; ++kc)
            qf[kc] = *(const bf16x8*)(qrow + kc * 32);
    }

    f32x4 agg[16];
    #pragma unroll
    for (int i = 0; i < 16; ++i) agg[i] = f32x4{0.f, 0.f, 0.f, 0.f};

    for (int jt = 0; jt < 128; ++jt) {
        const int j0 = jt * 64;
        __syncthreads();                       // prev-iter readers done
        for (int i = t; i < 64 * 32; i += 256) {   // K tile 64x256
            int row = i >> 5, g = i & 31;
            *(int4*)&Ks[row * 256 + ((g ^ (row & 7)) << 3)] =
                *(const int4*)(e + (size_t)(j0 + row) * 256 + g * 8);
        }
        for (int i = t; i < 256 * 8; i += 256) {   // V^T tile 256x64
            int row = i >> 3, g = i & 7;
            *(int4*)&Vs[row * 64 + ((g ^ (row & 7)) << 3)] =
                *(const int4*)(Xt + (size_t)row * 8192 + j0 + g * 8);
        }
        __syncthreads();

        // S = Q K^T : per-wave 16x64, m-split
        f32x4 s[4];
        #pragma unroll
        for (int nt = 0; nt < 4; ++nt) s[nt] = f32x4{0.f, 0.f, 0.f, 0.f};
        #pragma unroll
        for (int kc = 0; kc < 8; ++kc) {
            #pragma unroll
            for (int nt = 0; nt < 4; ++nt) {
                int row = nt * 16 + lr;
                bf16x8 kf = *(const bf16x8*)&Ks[row * 256 + (((kc*4 + q) ^ (row & 7)) << 3)];
                s[nt] = __builtin_amdgcn_mfma_f32_16x16x32_bf16(qf[kc], kf, s[nt], 0, 0, 0);
            }
        }
        // P = S/256 -> LDS (C-layout scatter, bf16)
        #pragma unroll
        for (int nt = 0; nt < 4; ++nt)
            #pragma unroll
            for (int r = 0; r < 4; ++r) {
                int m = w * 16 + q * 4 + r;
                int n = nt * 16 + lr;
                Ps[m * 64 + (((n >> 3) ^ (m & 7)) << 3) + (n & 7)] =
                    f2bf(s[nt][r] * (1.0f / 256.0f));
            }
        __syncthreads();

        // agg += P V : per-wave n-strip of 64 (n-split), all 64 m rows
        #pragma unroll
        for (int ks = 0; ks < 2; ++ks) {
            bf16x8 pf[4];
            #pragma unroll
            for (int mt = 0; mt < 4; ++mt) {
                int row = mt * 16 + lr;
                pf[mt] = *(const bf16x8*)&Ps[row * 64 + (((ks*4 + q) ^ (row & 7)) << 3)];
            }
            #pragma unroll
            for (int nt = 0; nt < 4; ++nt) {
                int row = w * 64 + nt * 16 + lr;
                bf16x8 vf = *(const bf16x8*)&Vs[row * 64 + (((ks*4 + q) ^ (row & 7)) << 3)];
                #pragma unroll
                for (int mt = 0; mt < 4; ++mt)
                    agg[mt * 4 + nt] = __builtin_amdgcn_mfma_f32_16x16x32_bf16(
                        pf[mt], vf, agg[mt * 4 + nt], 0, 0, 0);
            }
        }
    }

    const int colbase = 256 + sim * 256;
    #pragma unroll
    for (int mt = 0; mt < 4; ++mt)
        #pragma unroll
        for (int nt = 0; nt < 4; ++nt)
            #pragma unroll
            for (int r = 0; r < 4; ++r) {
                int m = m0 + mt * 16 + q * 4 + r;
                int n = w * 64 + nt * 16 + lr;
                h[(size_t)m * 768 + colbase + n] = f2bf(agg[mt * 4 + nt][r]);
            }
}

// ---------------------------------------------------------------- launch
extern "C" void kernel_launch(void* const* d_in, const int* in_sizes, int n_in,
                              void* d_out, int out_size, void* d_ws, size_t ws_size,
                              hipStream_t stream)
{
    const float* edge_x = (const float*)d_in[0];
    const float* W1 = (const float*)d_in[1];
    const float* b1 = (const float*)d_in[2];
    const float* W2 = (const float*)d_in[3];
    const float* b2 = (const float*)d_in[4];
    const float* Wo = (const float*)d_in[5];
    const float* bo = (const float*)d_in[6];

    char* ws = (char*)d_ws;
    short* h   = (short*)(ws);                  // [8192][768] bf16  12.0 MB
    short* Xt  = (short*)(ws + 12582912);       // [256][8192] bf16   4.0 MB
    short* e1  = (short*)(ws + 16777216);       // [8192][256] bf16   4.0 MB
    short* e2  = (short*)(ws + 20971520);       // [8192][256] bf16   4.0 MB
    short* Wt1 = (short*)(ws + 25165824);       // [256][256]  bf16
    short* Wt2 = (short*)(ws + 25296896);       // [256][256]  bf16
    short* Wto = (short*)(ws + 25427968);       // [256][768]  bf16

    prep_x<<<dim3(256, 8), dim3(32, 8), 0, stream>>>(edge_x, h, Xt);
    prep_w<<<dim3(8, 8),  dim3(32, 8), 0, stream>>>(W1, Wt1, 256, 256);
    prep_w<<<dim3(8, 8),  dim3(32, 8), 0, stream>>>(W2, Wt2, 256, 256);
    prep_w<<<dim3(24, 8), dim3(32, 8), 0, stream>>>(Wo, Wto, 768, 256);

    gemm_bias_relu<<<dim3(128, 4), 256, 0, stream>>>(h, 768, Wt1, 256, b1, e1, 1, 256);
    gemm_bias_relu<<<dim3(128, 4), 256, 0, stream>>>(h, 768, Wt2, 256, b2, e2, 1, 256);
    fused_simagg<<<dim3(128, 2), 256, 0, stream>>>(e1, e2, Xt, h);
    gemm_bias_relu<<<dim3(128, 4), 256, 0, stream>>>(h, 768, Wto, 768, bo, (float*)d_out, 0, 256);
}

// Round 2
// 529.820 us; speedup vs baseline: 1.2391x; 1.2391x over previous
//
#include <hip/hip_runtime.h>
#include <hip/hip_bf16.h>

// MPNN fused pipeline, bf16 MFMA (16x16x32), fp32 accum.
// R2 changes vs R1 (which was latency-bound at 1 block/CU, Occ=11.8%):
//  - j-split=4: each fused block covers a 2048-row j-range, writes bf16
//    partial aggs into widened h[8192][2304]; final GEMM reduces partials
//    via duplicated W_out rows (K=2304). Grid 256 -> 1024 blocks.
//  - Vs LDS tile removed: PV B-frags read 16B-aligned direct from Xt (L2).
//    LDS 72KB -> 40KB; __launch_bounds__(256,3) -> ~3 blocks/CU.
//  - 2 barriers/jt instead of 3 (restage after sync2 is race-free).

typedef short bf16x8 __attribute__((ext_vector_type(8)));
typedef float f32x4  __attribute__((ext_vector_type(4)));

__device__ inline short f2bf(float x) {                // fp32 -> bf16 RNE
    unsigned u = __builtin_bit_cast(unsigned, x);
    return (short)((u + 0x7fffu + ((u >> 16) & 1u)) >> 16);
}

// ---------------------------------------------------------------- prep_x
// edge_x fp32 -> bf16 into h[:,0:256] (ld=ldh) and Xt [256][8192]
__global__ void prep_x(const float* __restrict__ X, short* __restrict__ h,
                       int ldh, short* __restrict__ Xt)
{
    __shared__ short tile[32][33];
    const int r0 = blockIdx.x * 32, c0 = blockIdx.y * 32;
    const int tx = threadIdx.x, ty = threadIdx.y;      // 32 x 8
    #pragma unroll
    for (int i = 0; i < 4; ++i) {
        int row = ty + i * 8;
        short b = f2bf(X[(size_t)(r0 + row) * 256 + c0 + tx]);
        tile[row][tx] = b;
        h[(size_t)(r0 + row) * ldh + c0 + tx] = b;
    }
    __syncthreads();
    #pragma unroll
    for (int i = 0; i < 4; ++i) {
        int row = ty + i * 8;
        Xt[(size_t)(c0 + row) * 8192 + r0 + tx] = tile[tx][row];
    }
}

// ---------------------------------------------------------------- prep_w
// W fp32 [256][256] (rows start at W) -> bf16 Wt[n][k_off + k], ld=ldwt
__global__ void prep_w(const float* __restrict__ W, short* __restrict__ Wt,
                       int ldwt, int k_off)
{
    __shared__ short tile[32][33];
    const int k0 = blockIdx.x * 32, n0 = blockIdx.y * 32;
    const int tx = threadIdx.x, ty = threadIdx.y;
    #pragma unroll
    for (int i = 0; i < 4; ++i) {
        int row = ty + i * 8;
        tile[row][tx] = f2bf(W[(size_t)(k0 + row) * 256 + n0 + tx]);
    }
    __syncthreads();
    #pragma unroll
    for (int i = 0; i < 4; ++i) {
        int row = ty + i * 8;
        Wt[(size_t)(n0 + row) * ldwt + k_off + k0 + tx] = tile[tx][row];
    }
}

// -------------------------------------------------------- gemm_bias_relu
// out[m][n] = relu(sum_k A[m][k] * Bt[n][k] + bias[n]); Bt row stride = K
__global__ __launch_bounds__(256, 1)
void gemm_bias_relu(const short* __restrict__ A, int lda,
                    const short* __restrict__ Bt, int K,
                    const float* __restrict__ bias,
                    void* __restrict__ outp, int out_bf16, int ldo)
{
    const int m0 = blockIdx.x * 64, n0 = blockIdx.y * 64;
    const int t = threadIdx.x;
    const int w = t >> 6, l = t & 63, lr = l & 15, q = l >> 4;

    __shared__ __attribute__((aligned(16))) short As[64 * 64];
    __shared__ __attribute__((aligned(16))) short Bs[64 * 64];

    f32x4 acc[4];
    #pragma unroll
    for (int i = 0; i < 4; ++i) acc[i] = f32x4{0.f, 0.f, 0.f, 0.f};

    for (int k0 = 0; k0 < K; k0 += 64) {
        __syncthreads();
        for (int i = t; i < 64 * 8; i += 256) {
            int row = i >> 3, g = i & 7;
            *(int4*)&As[row * 64 + ((g ^ (row & 7)) << 3)] =
                *(const int4*)(A + (size_t)(m0 + row) * lda + k0 + g * 8);
            *(int4*)&Bs[row * 64 + ((g ^ (row & 7)) << 3)] =
                *(const int4*)(Bt + (size_t)(n0 + row) * K + k0 + g * 8);
        }
        __syncthreads();
        #pragma unroll
        for (int ks = 0; ks < 2; ++ks) {
            int arow = w * 16 + lr;
            bf16x8 af = *(const bf16x8*)&As[arow * 64 + (((ks*4 + q) ^ (arow & 7)) << 3)];
            #pragma unroll
            for (int nt = 0; nt < 4; ++nt) {
                int brow = nt * 16 + lr;
                bf16x8 bfg = *(const bf16x8*)&Bs[brow * 64 + (((ks*4 + q) ^ (brow & 7)) << 3)];
                acc[nt] = __builtin_amdgcn_mfma_f32_16x16x32_bf16(af, bfg, acc[nt], 0, 0, 0);
            }
        }
    }
    #pragma unroll
    for (int nt = 0; nt < 4; ++nt)
        #pragma unroll
        for (int r = 0; r < 4; ++r) {
            int m = m0 + w * 16 + q * 4 + r;      // C/D: row = quad*4 + reg
            int n = n0 + nt * 16 + lr;            //      col = lane & 15
            float v = acc[nt][r] + bias[n];
            v = v > 0.f ? v : 0.f;
            if (out_bf16) ((short*)outp)[(size_t)m * ldo + n] = f2bf(v);
            else          ((float*)outp)[(size_t)m * ldo + n] = v;
        }
}

// ---------------------------------------------------------- fused_simagg
// partial agg[m][:] = sum_{j in split} (e[m].e[j]/256) * X[j][:]
//   -> h[:, 256 + (sim*jsplit + s)*256 : +256]  (bf16 partial)
__global__ __launch_bounds__(256, 3)
void fused_simagg(const short* __restrict__ e1, const short* __restrict__ e2,
                  const short* __restrict__ Xt, short* __restrict__ h,
                  int ldh, int tiles_per_split)
{
    const int sim = blockIdx.y;
    const short* e = sim ? e2 : e1;
    const int m0 = blockIdx.x * 64;
    const int t = threadIdx.x;
    const int w = t >> 6, l = t & 63, lr = l & 15, q = l >> 4;

    __shared__ __attribute__((aligned(16))) short Ks[64 * 256]; // [j][k] swz
    __shared__ __attribute__((aligned(16))) short Ps[64 * 64];  // [m][j] swz

    // Q fragments resident in registers: rows m0 + w*16 + lr
    bf16x8 qf[8];
    {
        const short* qrow = e + (size_t)(m0 + w * 16 + lr) * 256 + q * 8;
        #pragma unroll
        for (int kc = 0; kc < 8; ++kc)
            qf[kc] = *(const bf16x8*)(qrow + kc * 32);
    }

    f32x4 agg[16];
    #pragma unroll
    for (int i = 0; i < 16; ++i) agg[i] = f32x4{0.f, 0.f, 0.f, 0.f};

    const int jbase = blockIdx.z * tiles_per_split;
    for (int jt = 0; jt < tiles_per_split; ++jt) {
        const int j0 = (jbase + jt) * 64;
        // stage K tile 64x256 (safe: all Ks readers done before prev sync2)
        for (int i = t; i < 64 * 32; i += 256) {
            int row = i >> 5, g = i & 31;
            *(int4*)&Ks[row * 256 + ((g ^ (row & 7)) << 3)] =
                *(const int4*)(e + (size_t)(j0 + row) * 256 + g * 8);
        }
        __syncthreads();   // sync1: staging done; prev pf reads done

        // S = Q K^T : per-wave 16x64, m-split
        f32x4 s[4];
        #pragma unroll
        for (int nt = 0; nt < 4; ++nt) s[nt] = f32x4{0.f, 0.f, 0.f, 0.f};
        #pragma unroll
        for (int kc = 0; kc < 8; ++kc) {
            #pragma unroll
            for (int nt = 0; nt < 4; ++nt) {
                int row = nt * 16 + lr;
                bf16x8 kf = *(const bf16x8*)&Ks[row * 256 + (((kc*4 + q) ^ (row & 7)) << 3)];
                s[nt] = __builtin_amdgcn_mfma_f32_16x16x32_bf16(qf[kc], kf, s[nt], 0, 0, 0);
            }
        }
        // P = S/256 -> LDS (C-layout scatter, bf16)
        #pragma unroll
        for (int nt = 0; nt < 4; ++nt)
            #pragma unroll
            for (int r = 0; r < 4; ++r) {
                int m = w * 16 + q * 4 + r;
                int n = nt * 16 + lr;
                Ps[m * 64 + (((n >> 3) ^ (m & 7)) << 3) + (n & 7)] =
                    f2bf(s[nt][r] * (1.0f / 256.0f));
            }
        __syncthreads();   // sync2: Ps visible

        // agg += P V : per-wave n-strip of 64; V-frags direct from Xt (L2)
        #pragma unroll
        for (int ks = 0; ks < 2; ++ks) {
            bf16x8 pf[4];
            #pragma unroll
            for (int mt = 0; mt < 4; ++mt) {
                int row = mt * 16 + lr;
                pf[mt] = *(const bf16x8*)&Ps[row * 64 + (((ks*4 + q) ^ (row & 7)) << 3)];
            }
            #pragma unroll
            for (int nt = 0; nt < 4; ++nt) {
                int n = w * 64 + nt * 16 + lr;
                bf16x8 vf = *(const bf16x8*)(Xt + (size_t)n * 8192 + j0 + (ks*4 + q) * 8);
                #pragma unroll
                for (int mt = 0; mt < 4; ++mt)
                    agg[mt * 4 + nt] = __builtin_amdgcn_mfma_f32_16x16x32_bf16(
                        pf[mt], vf, agg[mt * 4 + nt], 0, 0, 0);
            }
        }
    }

    const int colbase = 256 + (sim * gridDim.z + blockIdx.z) * 256;
    #pragma unroll
    for (int mt = 0; mt < 4; ++mt)
        #pragma unroll
        for (int nt = 0; nt < 4; ++nt)
            #pragma unroll
            for (int r = 0; r < 4; ++r) {
                int m = m0 + mt * 16 + q * 4 + r;
                int n = w * 64 + nt * 16 + lr;
                h[(size_t)m * ldh + colbase + n] = f2bf(agg[mt * 4 + nt][r]);
            }
}

// ---------------------------------------------------------------- launch
extern "C" void kernel_launch(void* const* d_in, const int* in_sizes, int n_in,
                              void* d_out, int out_size, void* d_ws, size_t ws_size,
                              hipStream_t stream)
{
    const float* edge_x = (const float*)d_in[0];
    const float* W1 = (const float*)d_in[1];
    const float* b1 = (const float*)d_in[2];
    const float* W2 = (const float*)d_in[3];
    const float* b2 = (const float*)d_in[4];
    const float* Wo = (const float*)d_in[5];
    const float* bo = (const float*)d_in[6];

    // ws layout (js=4): h 8192x2304 bf16 (37.75MB), Xt 4MB, e1/e2 4MB,
    // Wt1/Wt2 128KB, Wto 256x2304 bf16 (1.18MB) -> ~51.8MB total.
    const size_t need4 = (size_t)8192*2304*2 + 4194304*3 + 131072*2 + (size_t)2304*256*2;
    const int js = (ws_size >= need4) ? 4 : 1;     // fallback: R1 layout
    const int H = 256 + 2 * js * 256;              // 2304 or 768

    char* ws = (char*)d_ws;
    short* h   = (short*)ws;
    short* Xt  = (short*)(ws + (size_t)8192 * H * 2);
    short* e1  = (short*)((char*)Xt + 4194304);
    short* e2  = (short*)((char*)e1 + 4194304);
    short* Wt1 = (short*)((char*)e2 + 4194304);
    short* Wt2 = (short*)((char*)Wt1 + 131072);
    short* Wto = (short*)((char*)Wt2 + 131072);

    prep_x<<<dim3(256, 8), dim3(32, 8), 0, stream>>>(edge_x, h, H, Xt);
    prep_w<<<dim3(8, 8), dim3(32, 8), 0, stream>>>(W1, Wt1, 256, 0);
    prep_w<<<dim3(8, 8), dim3(32, 8), 0, stream>>>(W2, Wt2, 256, 0);
    for (int g = 0; g < 1 + 2 * js; ++g) {
        int srcrow = (g == 0) ? 0 : (g <= js ? 256 : 512);
        prep_w<<<dim3(8, 8), dim3(32, 8), 0, stream>>>(
            Wo + (size_t)srcrow * 256, Wto, H, g * 256);
    }

    gemm_bias_relu<<<dim3(128, 4), 256, 0, stream>>>(h, H, Wt1, 256, b1, e1, 1, 256);
    gemm_bias_relu<<<dim3(128, 4), 256, 0, stream>>>(h, H, Wt2, 256, b2, e2, 1, 256);
    fused_simagg<<<dim3(128, 2, js), 256, 0, stream>>>(e1, e2, Xt, h, H, 128 / js);
    gemm_bias_relu<<<dim3(128, 4), 256, 0, stream>>>(h, H, Wto, H, bo, (float*)d_out, 0, 256);
}

// Round 3
// 311.832 us; speedup vs baseline: 2.1053x; 1.6991x over previous
//
#include <hip/hip_runtime.h>
#include <hip/hip_bf16.h>

// MPNN fused pipeline, bf16 MFMA (16x16x32), fp32 accum.
// R3 changes vs R2 (fused was latency-bound: MfmaUtil 13.8%, 76% no-issue):
//  - K staging via global_load_lds(16B) into double-buffered Ks: prefetch of
//    tile jt+1 issues before the jt barrier -> drain overlaps QK compute.
//    e1/e2 are stored PRE-SWIZZLED in global (16B chunk c at c^(row&7)) so
//    the contiguous wave-uniform DMA lands in the conflict-free layout.
//  - ONE barrier per jt (was 2): Ps double-buffered, scatter(jt+1) and
//    PV-read(jt) use opposite parities. LDS 80KB -> 2 blocks/CU.
//  - S^T = K.Q^T (swapped MFMA operands): lane holds 4 consecutive j at
//    fixed m -> scatter is one aligned b64 store (was 4 scalar b16) ->
//    kills the 16.8M bank-conflict cycles.
//  - vf (Xt) register prefetch before QK; js=2 (512 blocks = 2/CU exactly).

typedef short bf16x8  __attribute__((ext_vector_type(8)));
typedef short short4v __attribute__((ext_vector_type(4)));
typedef float f32x4   __attribute__((ext_vector_type(4)));

__device__ inline short f2bf(float x) {                // fp32 -> bf16 RNE
    unsigned u = __builtin_bit_cast(unsigned, x);
    return (short)((u + 0x7fffu + ((u >> 16) & 1u)) >> 16);
}

__device__ inline void cp16_async(const short* g, short* l) {
    __builtin_amdgcn_global_load_lds(
        (const __attribute__((address_space(1))) unsigned int*)g,
        (__attribute__((address_space(3))) unsigned int*)l, 16, 0, 0);
}

// ---------------------------------------------------------------- prep_x
// edge_x fp32 -> bf16 into h[:,0:256] (ld=ldh) and Xt [256][8192]
__global__ void prep_x(const float* __restrict__ X, short* __restrict__ h,
                       int ldh, short* __restrict__ Xt)
{
    __shared__ short tile[32][33];
    const int r0 = blockIdx.x * 32, c0 = blockIdx.y * 32;
    const int tx = threadIdx.x, ty = threadIdx.y;      // 32 x 8
    #pragma unroll
    for (int i = 0; i < 4; ++i) {
        int row = ty + i * 8;
        short b = f2bf(X[(size_t)(r0 + row) * 256 + c0 + tx]);
        tile[row][tx] = b;
        h[(size_t)(r0 + row) * ldh + c0 + tx] = b;
    }
    __syncthreads();
    #pragma unroll
    for (int i = 0; i < 4; ++i) {
        int row = ty + i * 8;
        Xt[(size_t)(c0 + row) * 8192 + r0 + tx] = tile[tx][row];
    }
}

// ---------------------------------------------------------------- prep_w
// W fp32 [256][256] (rows start at W) -> bf16 Wt[n][k_off + k], ld=ldwt
__global__ void prep_w(const float* __restrict__ W, short* __restrict__ Wt,
                       int ldwt, int k_off)
{
    __shared__ short tile[32][33];
    const int k0 = blockIdx.x * 32, n0 = blockIdx.y * 32;
    const int tx = threadIdx.x, ty = threadIdx.y;
    #pragma unroll
    for (int i = 0; i < 4; ++i) {
        int row = ty + i * 8;
        tile[row][tx] = f2bf(W[(size_t)(k0 + row) * 256 + n0 + tx]);
    }
    __syncthreads();
    #pragma unroll
    for (int i = 0; i < 4; ++i) {
        int row = ty + i * 8;
        Wt[(size_t)(n0 + row) * ldwt + k_off + k0 + tx] = tile[tx][row];
    }
}

// -------------------------------------------------------- gemm_bias_relu
// out[m][n] = relu(sum_k A[m][k]*Bt[n][k] + bias[n]); Bt row stride = K.
// swz: bf16 output rows stored with 16B-chunk XOR swizzle (chunk c of row m
// lands at chunk c^(m&7)) so fused_simagg can DMA rows straight into its
// swizzled LDS layout.
__global__ __launch_bounds__(256, 1)
void gemm_bias_relu(const short* __restrict__ A, int lda,
                    const short* __restrict__ Bt, int K,
                    const float* __restrict__ bias,
                    void* __restrict__ outp, int out_bf16, int ldo, int swz)
{
    const int m0 = blockIdx.x * 64, n0 = blockIdx.y * 64;
    const int t = threadIdx.x;
    const int w = t >> 6, l = t & 63, lr = l & 15, q = l >> 4;

    __shared__ __attribute__((aligned(16))) short As[64 * 64];
    __shared__ __attribute__((aligned(16))) short Bs[64 * 64];

    f32x4 acc[4];
    #pragma unroll
    for (int i = 0; i < 4; ++i) acc[i] = f32x4{0.f, 0.f, 0.f, 0.f};

    for (int k0 = 0; k0 < K; k0 += 64) {
        __syncthreads();
        for (int i = t; i < 64 * 8; i += 256) {
            int row = i >> 3, g = i & 7;
            *(int4*)&As[row * 64 + ((g ^ (row & 7)) << 3)] =
                *(const int4*)(A + (size_t)(m0 + row) * lda + k0 + g * 8);
            *(int4*)&Bs[row * 64 + ((g ^ (row & 7)) << 3)] =
                *(const int4*)(Bt + (size_t)(n0 + row) * K + k0 + g * 8);
        }
        __syncthreads();
        #pragma unroll
        for (int ks = 0; ks < 2; ++ks) {
            int arow = w * 16 + lr;
            bf16x8 af = *(const bf16x8*)&As[arow * 64 + (((ks*4 + q) ^ (arow & 7)) << 3)];
            #pragma unroll
            for (int nt = 0; nt < 4; ++nt) {
                int brow = nt * 16 + lr;
                bf16x8 bfg = *(const bf16x8*)&Bs[brow * 64 + (((ks*4 + q) ^ (brow & 7)) << 3)];
                acc[nt] = __builtin_amdgcn_mfma_f32_16x16x32_bf16(af, bfg, acc[nt], 0, 0, 0);
            }
        }
    }
    #pragma unroll
    for (int nt = 0; nt < 4; ++nt)
        #pragma unroll
        for (int r = 0; r < 4; ++r) {
            int m = m0 + w * 16 + q * 4 + r;      // C/D: row = quad*4 + reg
            int n = n0 + nt * 16 + lr;            //      col = lane & 15
            float v = acc[nt][r] + bias[n];
            v = v > 0.f ? v : 0.f;
            if (out_bf16) {
                int col = swz ? ((((n >> 3) ^ (m & 7)) << 3) | (n & 7)) : n;
                ((short*)outp)[(size_t)m * ldo + col] = f2bf(v);
            } else {
                ((float*)outp)[(size_t)m * ldo + n] = v;
            }
        }
}

// ---------------------------------------------------------- fused_simagg
// partial agg[m][:] = sum_{j in split} (e[m].e[j]/256) * X[j][:]
//   -> h[:, 256 + (sim*jsplit + z)*256 : +256]  (bf16 partial)
// e1/e2 are chunk-swizzled in global (see gemm_bias_relu swz).
__global__ __launch_bounds__(256, 2)
void fused_simagg(const short* __restrict__ e1, const short* __restrict__ e2,
                  const short* __restrict__ Xt, short* __restrict__ h,
                  int ldh, int tiles_per_split)
{
    const int sim = blockIdx.y;
    const short* e = sim ? e2 : e1;
    const int m0 = blockIdx.x * 64;
    const int t = threadIdx.x;
    const int w = t >> 6, l = t & 63, lr = l & 15, q = l >> 4;

    __shared__ __attribute__((aligned(16))) short Ks[2][64 * 256]; // 64 KB
    __shared__ __attribute__((aligned(16))) short Ps[2][64 * 64];  // 16 KB

    // Q frags in registers: rows m0 + w*16 + lr (unswizzle the global chunks)
    bf16x8 qf[8];
    const int mrow = m0 + w * 16 + lr;
    {
        const short* qrow = e + (size_t)mrow * 256;
        #pragma unroll
        for (int kc = 0; kc < 8; ++kc)
            qf[kc] = *(const bf16x8*)(qrow + (((kc * 4 + q) ^ (mrow & 7)) << 3));
    }

    f32x4 agg[16];
    #pragma unroll
    for (int i = 0; i < 16; ++i) agg[i] = f32x4{0.f, 0.f, 0.f, 0.f};

    const int jbase = blockIdx.z * tiles_per_split;
    const int wub = t & ~63;                       // wave-uniform thread base

    // prologue: stage tile 0 into Ks[0]
    {
        const short* src = e + (size_t)(jbase * 64) * 256;
        #pragma unroll
        for (int it = 0; it < 8; ++it)
            cp16_async(src + (size_t)(it * 256 + t) * 8,
                       &Ks[0][(size_t)(it * 256 + wub) * 8]);
    }
    __syncthreads();

    for (int jt = 0; jt < tiles_per_split; ++jt) {
        const int cur = jt & 1, nxt = cur ^ 1;
        const int j0 = (jbase + jt) * 64;

        // async prefetch of next K tile into Ks[nxt] (drains at the barrier,
        // overlapped by vfr + QK + scatter)
        if (jt + 1 < tiles_per_split) {
            const short* src = e + (size_t)(j0 + 64) * 256;
            #pragma unroll
            for (int it = 0; it < 8; ++it)
                cp16_async(src + (size_t)(it * 256 + t) * 8,
                           &Ks[nxt][(size_t)(it * 256 + wub) * 8]);
        }

        // vf register prefetch for current tile (independent global loads)
        bf16x8 vfr[8];
        #pragma unroll
        for (int ks = 0; ks < 2; ++ks)
            #pragma unroll
            for (int nt = 0; nt < 4; ++nt) {
                int n = w * 64 + nt * 16 + lr;
                vfr[ks * 4 + nt] =
                    *(const bf16x8*)(Xt + (size_t)n * 8192 + j0 + (ks * 4 + q) * 8);
            }

        // S^T = K Q^T : A = K rows (LDS), B = Q rows (regs)
        // lane (q,lr) -> S^T[j = nt*16 + q*4 + r][m = w*16 + lr]
        const short* Kb = &Ks[cur][0];
        f32x4 s[4];
        #pragma unroll
        for (int nt = 0; nt < 4; ++nt) s[nt] = f32x4{0.f, 0.f, 0.f, 0.f};
        #pragma unroll
        for (int kc = 0; kc < 8; ++kc) {
            #pragma unroll
            for (int nt = 0; nt < 4; ++nt) {
                int row = nt * 16 + lr;
                bf16x8 kf = *(const bf16x8*)&Kb[row * 256 + (((kc*4 + q) ^ (row & 7)) << 3)];
                s[nt] = __builtin_amdgcn_mfma_f32_16x16x32_bf16(kf, qf[kc], s[nt], 0, 0, 0);
            }
        }

        // P scatter: 4 consecutive j at fixed m -> one aligned b64 per nt
        {
            const int mloc = w * 16 + lr;
            #pragma unroll
            for (int nt = 0; nt < 4; ++nt) {
                int jj = nt * 16 + q * 4;
                int off = mloc * 64 + (((jj >> 3) ^ (mloc & 7)) << 3) + (jj & 7);
                short4v pk = { f2bf(s[nt][0] * (1.0f/256.0f)),
                               f2bf(s[nt][1] * (1.0f/256.0f)),
                               f2bf(s[nt][2] * (1.0f/256.0f)),
                               f2bf(s[nt][3] * (1.0f/256.0f)) };
                *(short4v*)&Ps[cur][off] = pk;
            }
        }
        __syncthreads();   // the ONLY barrier per jt

        // agg += P V : pf from Ps[cur], vf from prefetched regs
        #pragma unroll
        for (int ks = 0; ks < 2; ++ks) {
            bf16x8 pf[4];
            #pragma unroll
            for (int mt = 0; mt < 4; ++mt) {
                int row = mt * 16 + lr;
                pf[mt] = *(const bf16x8*)&Ps[cur][row * 64 + (((ks*4 + q) ^ (row & 7)) << 3)];
            }
            #pragma unroll
            for (int nt = 0; nt < 4; ++nt) {
                #pragma unroll
                for (int mt = 0; mt < 4; ++mt)
                    agg[mt * 4 + nt] = __builtin_amdgcn_mfma_f32_16x16x32_bf16(
                        pf[mt], vfr[ks * 4 + nt], agg[mt * 4 + nt], 0, 0, 0);
            }
        }
    }

    const int colbase = 256 + (sim * gridDim.z + blockIdx.z) * 256;
    #pragma unroll
    for (int mt = 0; mt < 4; ++mt)
        #pragma unroll
        for (int nt = 0; nt < 4; ++nt)
            #pragma unroll
            for (int r = 0; r < 4; ++r) {
                int m = m0 + mt * 16 + q * 4 + r;
                int n = w * 64 + nt * 16 + lr;
                h[(size_t)m * ldh + colbase + n] = f2bf(agg[mt * 4 + nt][r]);
            }
}

// ---------------------------------------------------------------- launch
extern "C" void kernel_launch(void* const* d_in, const int* in_sizes, int n_in,
                              void* d_out, int out_size, void* d_ws, size_t ws_size,
                              hipStream_t stream)
{
    const float* edge_x = (const float*)d_in[0];
    const float* W1 = (const float*)d_in[1];
    const float* b1 = (const float*)d_in[2];
    const float* W2 = (const float*)d_in[3];
    const float* b2 = (const float*)d_in[4];
    const float* Wo = (const float*)d_in[5];
    const float* bo = (const float*)d_in[6];

    // js=2: h 8192x1280 bf16 (20MB) + Xt/e1/e2 4MB + Wt1/Wt2 + Wto -> ~34MB
    const size_t need2 = (size_t)8192*1280*2 + 4194304u*3 + 131072u*2 + (size_t)1280*256*2;
    const int js = (ws_size >= need2) ? 2 : 1;
    const int H = 256 + 2 * js * 256;              // 1280 or 768

    char* ws = (char*)d_ws;
    short* h   = (short*)ws;
    short* Xt  = (short*)(ws + (size_t)8192 * H * 2);
    short* e1  = (short*)((char*)Xt + 4194304);
    short* e2  = (short*)((char*)e1 + 4194304);
    short* Wt1 = (short*)((char*)e2 + 4194304);
    short* Wt2 = (short*)((char*)Wt1 + 131072);
    short* Wto = (short*)((char*)Wt2 + 131072);

    prep_x<<<dim3(256, 8), dim3(32, 8), 0, stream>>>(edge_x, h, H, Xt);
    prep_w<<<dim3(8, 8), dim3(32, 8), 0, stream>>>(W1, Wt1, 256, 0);
    prep_w<<<dim3(8, 8), dim3(32, 8), 0, stream>>>(W2, Wt2, 256, 0);
    for (int g = 0; g < 1 + 2 * js; ++g) {
        int srcrow = (g == 0) ? 0 : (g <= js ? 256 : 512);
        prep_w<<<dim3(8, 8), dim3(32, 8), 0, stream>>>(
            Wo + (size_t)srcrow * 256, Wto, H, g * 256);
    }

    gemm_bias_relu<<<dim3(128, 4), 256, 0, stream>>>(h, H, Wt1, 256, b1, e1, 1, 256, 1);
    gemm_bias_relu<<<dim3(128, 4), 256, 0, stream>>>(h, H, Wt2, 256, b2, e2, 1, 256, 1);
    fused_simagg<<<dim3(128, 2, js), 256, 0, stream>>>(e1, e2, Xt, h, H, 128 / js);
    gemm_bias_relu<<<dim3(128, 4), 256, 0, stream>>>(h, H, Wto, H, bo, (float*)d_out, 0, 256, 0);
}

// Round 4
// 288.393 us; speedup vs baseline: 2.2764x; 1.0813x over previous
//
#include <hip/hip_runtime.h>
#include <hip/hip_bf16.h>

// MPNN fused pipeline, bf16 MFMA (16x16x32), fp32 accum.
// R4 changes vs R3 (fused LDS-pipe-bound: kf reads = 4x amplified):
//  - QK quadrant partition: wave w handles (m-half w&1, j-half w>>1), reads
//    only its 32 K-rows -> kf b128 reads per wave/jt 32 -> 16 (LDS traffic
//    for kf halves). qf doubles to 64 VGPRs (still fits 8 waves/CU).
//  - XCD swizzle: 2 XCDs per (sim,jsplit) quadrant -> one 4MB e per XCD L2.
//  - 7 prep_w launches -> 1 prep_w_all launch.
// Conflict-counter note: SQ_LDS_BANK_CONFLICT ~= 4 x (#ds_read_b128), an
// inherent b128 cost (m134: 12 cyc vs 8 ideal), not a fixable pattern.

typedef short bf16x8  __attribute__((ext_vector_type(8)));
typedef short short4v __attribute__((ext_vector_type(4)));
typedef float f32x4   __attribute__((ext_vector_type(4)));

__device__ inline short f2bf(float x) {                // fp32 -> bf16 RNE
    unsigned u = __builtin_bit_cast(unsigned, x);
    return (short)((u + 0x7fffu + ((u >> 16) & 1u)) >> 16);
}

__device__ inline void cp16_async(const short* g, short* l) {
    __builtin_amdgcn_global_load_lds(
        (const __attribute__((address_space(1))) unsigned int*)g,
        (__attribute__((address_space(3))) unsigned int*)l, 16, 0, 0);
}

// ---------------------------------------------------------------- prep_x
__global__ void prep_x(const float* __restrict__ X, short* __restrict__ h,
                       int ldh, short* __restrict__ Xt)
{
    __shared__ short tile[32][33];
    const int r0 = blockIdx.x * 32, c0 = blockIdx.y * 32;
    const int tx = threadIdx.x, ty = threadIdx.y;      // 32 x 8
    #pragma unroll
    for (int i = 0; i < 4; ++i) {
        int row = ty + i * 8;
        short b = f2bf(X[(size_t)(r0 + row) * 256 + c0 + tx]);
        tile[row][tx] = b;
        h[(size_t)(r0 + row) * ldh + c0 + tx] = b;
    }
    __syncthreads();
    #pragma unroll
    for (int i = 0; i < 4; ++i) {
        int row = ty + i * 8;
        Xt[(size_t)(c0 + row) * 8192 + r0 + tx] = tile[tx][row];
    }
}

// -------------------------------------------------------------- prep_w_all
// z=0: W1->Wt1; z=1: W2->Wt2; z>=2: Wo 256-row group (z-2) -> Wto k-block.
__global__ void prep_w_all(const float* __restrict__ W1,
                           const float* __restrict__ W2,
                           const float* __restrict__ Wo,
                           short* __restrict__ Wt1, short* __restrict__ Wt2,
                           short* __restrict__ Wto, int H, int js)
{
    const int z = blockIdx.z;
    const float* src; short* dst; int ldwt, k_off;
    if (z == 0)      { src = W1; dst = Wt1; ldwt = 256; k_off = 0; }
    else if (z == 1) { src = W2; dst = Wt2; ldwt = 256; k_off = 0; }
    else {
        int g = z - 2;                         // 0 .. 2*js
        int srcrow = (g == 0) ? 0 : (g <= js ? 256 : 512);
        src = Wo + (size_t)srcrow * 256; dst = Wto; ldwt = H; k_off = g * 256;
    }
    __shared__ short tile[32][33];
    const int k0 = blockIdx.x * 32, n0 = blockIdx.y * 32;
    const int tx = threadIdx.x, ty = threadIdx.y;
    #pragma unroll
    for (int i = 0; i < 4; ++i) {
        int row = ty + i * 8;
        tile[row][tx] = f2bf(src[(size_t)(k0 + row) * 256 + n0 + tx]);
    }
    __syncthreads();
    #pragma unroll
    for (int i = 0; i < 4; ++i) {
        int row = ty + i * 8;
        dst[(size_t)(n0 + row) * ldwt + k_off + k0 + tx] = tile[tx][row];
    }
}

// -------------------------------------------------------- gemm_bias_relu
__global__ __launch_bounds__(256, 1)
void gemm_bias_relu(const short* __restrict__ A, int lda,
                    const short* __restrict__ Bt, int K,
                    const float* __restrict__ bias,
                    void* __restrict__ outp, int out_bf16, int ldo, int swz)
{
    const int m0 = blockIdx.x * 64, n0 = blockIdx.y * 64;
    const int t = threadIdx.x;
    const int w = t >> 6, l = t & 63, lr = l & 15, q = l >> 4;

    __shared__ __attribute__((aligned(16))) short As[64 * 64];
    __shared__ __attribute__((aligned(16))) short Bs[64 * 64];

    f32x4 acc[4];
    #pragma unroll
    for (int i = 0; i < 4; ++i) acc[i] = f32x4{0.f, 0.f, 0.f, 0.f};

    for (int k0 = 0; k0 < K; k0 += 64) {
        __syncthreads();
        for (int i = t; i < 64 * 8; i += 256) {
            int row = i >> 3, g = i & 7;
            *(int4*)&As[row * 64 + ((g ^ (row & 7)) << 3)] =
                *(const int4*)(A + (size_t)(m0 + row) * lda + k0 + g * 8);
            *(int4*)&Bs[row * 64 + ((g ^ (row & 7)) << 3)] =
                *(const int4*)(Bt + (size_t)(n0 + row) * K + k0 + g * 8);
        }
        __syncthreads();
        #pragma unroll
        for (int ks = 0; ks < 2; ++ks) {
            int arow = w * 16 + lr;
            bf16x8 af = *(const bf16x8*)&As[arow * 64 + (((ks*4 + q) ^ (arow & 7)) << 3)];
            #pragma unroll
            for (int nt = 0; nt < 4; ++nt) {
                int brow = nt * 16 + lr;
                bf16x8 bfg = *(const bf16x8*)&Bs[brow * 64 + (((ks*4 + q) ^ (brow & 7)) << 3)];
                acc[nt] = __builtin_amdgcn_mfma_f32_16x16x32_bf16(af, bfg, acc[nt], 0, 0, 0);
            }
        }
    }
    #pragma unroll
    for (int nt = 0; nt < 4; ++nt)
        #pragma unroll
        for (int r = 0; r < 4; ++r) {
            int m = m0 + w * 16 + q * 4 + r;      // C/D: row = quad*4 + reg
            int n = n0 + nt * 16 + lr;            //      col = lane & 15
            float v = acc[nt][r] + bias[n];
            v = v > 0.f ? v : 0.f;
            if (out_bf16) {
                int col = swz ? ((((n >> 3) ^ (m & 7)) << 3) | (n & 7)) : n;
                ((short*)outp)[(size_t)m * ldo + col] = f2bf(v);
            } else {
                ((float*)outp)[(size_t)m * ldo + n] = v;
            }
        }
}

// ---------------------------------------------------------- fused_simagg
// partial agg[m][:] = sum_{j in split} (e[m].e[j]/256) * X[j][:]
//   -> h[:, 256 + (sim*jsplit + jz)*256 : +256]  (bf16 partial)
__global__ __launch_bounds__(256, 2)
void fused_simagg(const short* __restrict__ e1, const short* __restrict__ e2,
                  const short* __restrict__ Xt, short* __restrict__ h,
                  int ldh, int tiles_per_split)
{
    // XCD swizzle: with grid (128,2,2), give each (sim,jz) quadrant to a
    // fixed pair of XCDs (dispatch round-robins linear id % 8).
    int sim, jz, mx;
    if (gridDim.x == 128 && gridDim.z == 2) {
        int flat = blockIdx.x + 128 * (blockIdx.y + 2 * blockIdx.z);
        int xcd = flat & 7, slot = flat >> 3;
        int quad = xcd >> 1;
        sim = quad >> 1; jz = quad & 1;
        mx = slot + (xcd & 1) * 64;
    } else { sim = blockIdx.y; jz = blockIdx.z; mx = blockIdx.x; }

    const short* e = sim ? e2 : e1;
    const int m0 = mx * 64;
    const int t = threadIdx.x;
    const int w = t >> 6, l = t & 63, lr = l & 15, q = l >> 4;
    const int mh = (w & 1) * 32;               // m-half of this wave
    const int jh = (w >> 1) * 32;              // j-half of this wave

    __shared__ __attribute__((aligned(16))) short Ks[2][64 * 256]; // 64 KB
    __shared__ __attribute__((aligned(16))) short Ps[2][64 * 64];  // 16 KB

    // Q frags: rows m0 + mh + ms*16 + lr  (unswizzle global chunks)
    bf16x8 qf[2][8];
    #pragma unroll
    for (int ms = 0; ms < 2; ++ms) {
        const int mrow = m0 + mh + ms * 16 + lr;
        const short* qrow = e + (size_t)mrow * 256;
        #pragma unroll
        for (int kc = 0; kc < 8; ++kc)
            qf[ms][kc] = *(const bf16x8*)(qrow + (((kc * 4 + q) ^ (mrow & 7)) << 3));
    }

    f32x4 agg[16];
    #pragma unroll
    for (int i = 0; i < 16; ++i) agg[i] = f32x4{0.f, 0.f, 0.f, 0.f};

    const int jbase = jz * tiles_per_split;
    const int wub = t & ~63;                   // wave-uniform thread base

    // prologue: stage tile 0 into Ks[0]
    {
        const short* src = e + (size_t)(jbase * 64) * 256;
        #pragma unroll
        for (int it = 0; it < 8; ++it)
            cp16_async(src + (size_t)(it * 256 + t) * 8,
                       &Ks[0][(size_t)(it * 256 + wub) * 8]);
    }
    __syncthreads();

    for (int jt = 0; jt < tiles_per_split; ++jt) {
        const int cur = jt & 1, nxt = cur ^ 1;
        const int j0 = (jbase + jt) * 64;

        // async prefetch of next K tile (drains at the barrier)
        if (jt + 1 < tiles_per_split) {
            const short* src = e + (size_t)(j0 + 64) * 256;
            #pragma unroll
            for (int it = 0; it < 8; ++it)
                cp16_async(src + (size_t)(it * 256 + t) * 8,
                           &Ks[nxt][(size_t)(it * 256 + wub) * 8]);
        }

        // vf register prefetch for current tile
        bf16x8 vfr[8];
        #pragma unroll
        for (int ks = 0; ks < 2; ++ks)
            #pragma unroll
            for (int nt = 0; nt < 4; ++nt) {
                int n = w * 64 + nt * 16 + lr;
                vfr[ks * 4 + nt] =
                    *(const bf16x8*)(Xt + (size_t)n * 8192 + j0 + (ks * 4 + q) * 8);
            }

        // S^T quadrant: wave reads only its 32 K-rows (jh .. jh+31)
        const short* Kb = &Ks[cur][0];
        f32x4 s[2][2];                          // [js2][ms]
        #pragma unroll
        for (int a = 0; a < 2; ++a)
            #pragma unroll
            for (int b = 0; b < 2; ++b) s[a][b] = f32x4{0.f, 0.f, 0.f, 0.f};
        #pragma unroll
        for (int kc = 0; kc < 8; ++kc) {
            #pragma unroll
            for (int js2 = 0; js2 < 2; ++js2) {
                int row = jh + js2 * 16 + lr;
                bf16x8 kf = *(const bf16x8*)&Kb[row * 256 + (((kc*4 + q) ^ (row & 7)) << 3)];
                #pragma unroll
                for (int ms = 0; ms < 2; ++ms)
                    s[js2][ms] = __builtin_amdgcn_mfma_f32_16x16x32_bf16(
                        kf, qf[ms][kc], s[js2][ms], 0, 0, 0);
            }
        }

        // P scatter: 4 consecutive j at fixed m -> one aligned b64 each
        #pragma unroll
        for (int js2 = 0; js2 < 2; ++js2)
            #pragma unroll
            for (int ms = 0; ms < 2; ++ms) {
                int mloc = mh + ms * 16 + lr;
                int jj = jh + js2 * 16 + q * 4;
                int off = mloc * 64 + (((jj >> 3) ^ (mloc & 7)) << 3) + (jj & 7);
                short4v pk = { f2bf(s[js2][ms][0] * (1.0f/256.0f)),
                               f2bf(s[js2][ms][1] * (1.0f/256.0f)),
                               f2bf(s[js2][ms][2] * (1.0f/256.0f)),
                               f2bf(s[js2][ms][3] * (1.0f/256.0f)) };
                *(short4v*)&Ps[cur][off] = pk;
            }
        __syncthreads();   // the ONLY barrier per jt

        // agg += P V : pf from Ps[cur], vf from prefetched regs
        #pragma unroll
        for (int ks = 0; ks < 2; ++ks) {
            bf16x8 pf[4];
            #pragma unroll
            for (int mt = 0; mt < 4; ++mt) {
                int row = mt * 16 + lr;
                pf[mt] = *(const bf16x8*)&Ps[cur][row * 64 + (((ks*4 + q) ^ (row & 7)) << 3)];
            }
            #pragma unroll
            for (int nt = 0; nt < 4; ++nt) {
                #pragma unroll
                for (int mt = 0; mt < 4; ++mt)
                    agg[mt * 4 + nt] = __builtin_amdgcn_mfma_f32_16x16x32_bf16(
                        pf[mt], vfr[ks * 4 + nt], agg[mt * 4 + nt], 0, 0, 0);
            }
        }
    }

    const int colbase = 256 + (sim * gridDim.z + jz) * 256;
    #pragma unroll
    for (int mt = 0; mt < 4; ++mt)
        #pragma unroll
        for (int nt = 0; nt < 4; ++nt)
            #pragma unroll
            for (int r = 0; r < 4; ++r) {
                int m = m0 + mt * 16 + q * 4 + r;
                int n = w * 64 + nt * 16 + lr;
                h[(size_t)m * ldh + colbase + n] = f2bf(agg[mt * 4 + nt][r]);
            }
}

// ---------------------------------------------------------------- launch
extern "C" void kernel_launch(void* const* d_in, const int* in_sizes, int n_in,
                              void* d_out, int out_size, void* d_ws, size_t ws_size,
                              hipStream_t stream)
{
    const float* edge_x = (const float*)d_in[0];
    const float* W1 = (const float*)d_in[1];
    const float* b1 = (const float*)d_in[2];
    const float* W2 = (const float*)d_in[3];
    const float* b2 = (const float*)d_in[4];
    const float* Wo = (const float*)d_in[5];
    const float* bo = (const float*)d_in[6];

    const size_t need2 = (size_t)8192*1280*2 + 4194304u*3 + 131072u*2 + (size_t)1280*256*2;
    const int js = (ws_size >= need2) ? 2 : 1;
    const int H = 256 + 2 * js * 256;              // 1280 or 768

    char* ws = (char*)d_ws;
    short* h   = (short*)ws;
    short* Xt  = (short*)(ws + (size_t)8192 * H * 2);
    short* e1  = (short*)((char*)Xt + 4194304);
    short* e2  = (short*)((char*)e1 + 4194304);
    short* Wt1 = (short*)((char*)e2 + 4194304);
    short* Wt2 = (short*)((char*)Wt1 + 131072);
    short* Wto = (short*)((char*)Wt2 + 131072);

    prep_x<<<dim3(256, 8), dim3(32, 8), 0, stream>>>(edge_x, h, H, Xt);
    prep_w_all<<<dim3(8, 8, 3 + 2 * js), dim3(32, 8), 0, stream>>>(
        W1, W2, Wo, Wt1, Wt2, Wto, H, js);

    gemm_bias_relu<<<dim3(128, 4), 256, 0, stream>>>(h, H, Wt1, 256, b1, e1, 1, 256, 1);
    gemm_bias_relu<<<dim3(128, 4), 256, 0, stream>>>(h, H, Wt2, 256, b2, e2, 1, 256, 1);
    fused_simagg<<<dim3(128, 2, js), 256, 0, stream>>>(e1, e2, Xt, h, H, 128 / js);
    gemm_bias_relu<<<dim3(128, 4), 256, 0, stream>>>(h, H, Wto, H, bo, (float*)d_out, 0, 256, 0);
}